// Round 1
// baseline (456.585 us; speedup 1.0000x reference)
//
#include <hip/hip_runtime.h>
#include <math.h>

// Problem constants (fixed by the reference).
constexpr int Bn = 8192;
constexpr int Nn = 128;
constexpr int Mn = 64;
constexpr float kEPS = 1e-8f;

// LDS memory tile row stride padded 64 -> 68 floats (17 float4) so the
// per-row reductions (row-major reads with stride N*4B) hit all 32 banks
// instead of aliasing onto bank 0 (64 floats = 2*32 banks).
constexpr int ROWP4 = 17;

__global__ __launch_bounds__(256)
void ntm_step(const float* __restrict__ memory,
              const float* __restrict__ prev_w,
              const float* __restrict__ kvec,
              const float* __restrict__ beta,
              const float* __restrict__ gate,
              const float* __restrict__ shift,
              const float* __restrict__ gamma,
              const float* __restrict__ erase,
              const float* __restrict__ addv,
              float* __restrict__ out_read,
              float* __restrict__ out_mem,
              float* __restrict__ out_w)
{
  __shared__ float lm[Nn * ROWP4 * 4];   // padded memory tile, 34816 B
  __shared__ float lk[Mn];
  __shared__ float le[Mn];
  __shared__ float la[Mn];
  __shared__ float llog[Nn];             // beta * cos
  __shared__ float lwg[Nn];              // interpolated weighting
  __shared__ float lw[Nn];               // final weighting
  __shared__ float lpart[16 * Mn];       // read-GEMV partials, 4096 B

  const int b = blockIdx.x;
  const int t = threadIdx.x;

  const float4* gm4 = (const float4*)(memory + (size_t)b * (Nn * Mn));

  // Stage small per-batch vectors.
  if (t < Mn) {
    lk[t] = kvec[b * Mn + t];
    le[t] = erase[b * Mn + t];
    la[t] = addv[b * Mn + t];
  }

  // Stage the 32 KB memory tile: 2048 float4, 8 per thread, coalesced.
  float4 stg[8];
  #pragma unroll
  for (int i = 0; i < 8; ++i) stg[i] = gm4[t + 256 * i];
  #pragma unroll
  for (int i = 0; i < 8; ++i) {
    const int f = t + 256 * i;
    ((float4*)lm)[(f >> 4) * ROWP4 + (f & 15)] = stg[i];
  }
  __syncthreads();

  // --- content addressing: per-row dot & norms, 2 threads per row ---
  {
    const int n = t >> 1;
    const int half = t & 1;
    const float4* r4 = ((const float4*)lm) + n * ROWP4 + half * 8;
    const float4* k4 = ((const float4*)lk) + half * 8;
    float dot = 0.f, sq = 0.f, ksq = 0.f;
    #pragma unroll
    for (int j = 0; j < 8; ++j) {
      const float4 v = r4[j];
      const float4 kk = k4[j];
      dot += v.x * kk.x + v.y * kk.y + v.z * kk.z + v.w * kk.w;
      sq  += v.x * v.x + v.y * v.y + v.z * v.z + v.w * v.w;
      ksq += kk.x * kk.x + kk.y * kk.y + kk.z * kk.z + kk.w * kk.w;
    }
    // pair-combine: lanes (2n, 2n+1) are adjacent within a wave
    dot += __shfl_xor(dot, 1);
    sq  += __shfl_xor(sq, 1);
    ksq += __shfl_xor(ksq, 1);   // ksq is now the FULL ||k||^2 (halves cover 0..31 / 32..63)
    if (half == 0) {
      const float kn = fmaxf(sqrtf(ksq), kEPS);
      const float mn = fmaxf(sqrtf(sq), kEPS);
      llog[n] = beta[b] * (dot / (kn * mn));
    }
  }
  __syncthreads();

  // --- softmax over N + interpolation with prev_w (wave 0, 2 rows/lane) ---
  if (t < 64) {
    const float v0 = llog[t], v1 = llog[t + 64];
    float mx = fmaxf(v0, v1);
    #pragma unroll
    for (int o = 1; o < 64; o <<= 1) mx = fmaxf(mx, __shfl_xor(mx, o));
    const float e0 = __expf(v0 - mx), e1 = __expf(v1 - mx);
    float sum = e0 + e1;
    #pragma unroll
    for (int o = 1; o < 64; o <<= 1) sum += __shfl_xor(sum, o);
    const float inv = 1.f / sum;
    const float gv = gate[b];
    lwg[t]      = gv * (e0 * inv) + (1.f - gv) * prev_w[b * Nn + t];
    lwg[t + 64] = gv * (e1 * inv) + (1.f - gv) * prev_w[b * Nn + t + 64];
  }
  __syncthreads();

  // --- circular shift + sharpen + renormalize (wave 0) ---
  if (t < 64) {
    const float s0 = shift[0], s1 = shift[1], s2 = shift[2];
    const int n0 = t, n1 = t + 64;
    const float wt0 = s0 * lwg[(n0 - 1) & 127] + s1 * lwg[n0] + s2 * lwg[(n0 + 1) & 127];
    const float wt1 = s0 * lwg[(n1 - 1) & 127] + s1 * lwg[n1] + s2 * lwg[(n1 + 1) & 127];
    const float yv = gamma[b];
    const float wp0 = powf(wt0, yv);
    const float wp1 = powf(wt1, yv);
    float sum = wp0 + wp1;
    #pragma unroll
    for (int o = 1; o < 64; o <<= 1) sum += __shfl_xor(sum, o);
    const float inv = 1.f / sum;
    const float w0 = wp0 * inv, w1 = wp1 * inv;
    lw[n0] = w0;
    lw[n1] = w1;
    out_w[b * Nn + n0] = w0;
    out_w[b * Nn + n1] = w1;
  }
  __syncthreads();

  // --- erase/add write (from OLD memory) fused with read-GEMV partials ---
  {
    const int c4 = t & 15;       // fixed 4-column group per thread
    const int rbase = t >> 4;    // rows rbase + 16*i
    const float4 ev = ((const float4*)le)[c4];
    const float4 av = ((const float4*)la)[c4];
    float4* om4 = (float4*)(out_mem + (size_t)b * (Nn * Mn));
    float4 racc = make_float4(0.f, 0.f, 0.f, 0.f);
    #pragma unroll
    for (int i = 0; i < 8; ++i) {
      const int row = rbase + 16 * i;
      const float wv = lw[row];                       // broadcast (16 lanes/addr)
      const float4 mv = ((const float4*)lm)[row * ROWP4 + c4];
      float4 o;
      o.x = mv.x * (1.f - wv * ev.x) + wv * av.x;
      o.y = mv.y * (1.f - wv * ev.y) + wv * av.y;
      o.z = mv.z * (1.f - wv * ev.z) + wv * av.z;
      o.w = mv.w * (1.f - wv * ev.w) + wv * av.w;
      om4[t + 256 * i] = o;                           // coalesced float4 store
      racc.x += wv * mv.x;
      racc.y += wv * mv.y;
      racc.z += wv * mv.z;
      racc.w += wv * mv.w;
    }
    ((float4*)lpart)[rbase * 16 + c4] = racc;
  }
  __syncthreads();

  // --- combine 16 read partials per column ---
  if (t < Mn) {
    float acc = 0.f;
    #pragma unroll
    for (int p = 0; p < 16; ++p) acc += lpart[p * Mn + t];
    out_read[b * Mn + t] = acc;
  }
}

extern "C" void kernel_launch(void* const* d_in, const int* in_sizes, int n_in,
                              void* d_out, int out_size, void* d_ws, size_t ws_size,
                              hipStream_t stream) {
  const float* memory = (const float*)d_in[0];
  const float* prev_w = (const float*)d_in[1];
  const float* k      = (const float*)d_in[2];
  const float* beta   = (const float*)d_in[3];
  const float* g      = (const float*)d_in[4];
  const float* s      = (const float*)d_in[5];
  const float* y      = (const float*)d_in[6];
  const float* e      = (const float*)d_in[7];
  const float* a      = (const float*)d_in[8];

  float* out = (float*)d_out;
  // return order: read (B*M), mem_new (B*N*M), w (B*N)
  float* out_read = out;
  float* out_mem  = out + (size_t)Bn * Mn;
  float* out_w    = out + (size_t)Bn * Mn + (size_t)Bn * Nn * Mn;

  ntm_step<<<Bn, 256, 0, stream>>>(memory, prev_w, k, beta, g, s, y, e, a,
                                   out_read, out_mem, out_w);
}